// Round 13
// baseline (31.473 us; speedup 1.0000x reference)
//
#include <hip/hip_runtime.h>
#include <math.h>

// DeepFeatureLoss: B=2, N=4096, D=32, fp32 in/out.
// out[0..1] = ce_loss[b], out[2..3] = reg_loss[b].
//
// ce_i = log(s_f) - t/s_p  (softmax max pinned at 0; dists <= 0):
//   s_p = sum_j exp(pd_ij), t = sum_j exp(pd_ij)*fd_ij, s_f = sum_j exp(fd_ij)
// exp2 folding: points *PSC, features *FSC, norms *L2E; t *= LN2 at end.
//
// R13 = R12 + MI=4 (validated stall lever, 2nd application):
//   block = (i-quad, 64 rows) x (j-quarter, 1024 cols), 8 waves x 8 iters.
//   Per iter ONE bfrag+pw load -> 4 MFMAs + 4 epilogues. Wave-iter stalls
//   16 -> 8 (R12 calibration: ~0.28us wall per removed stall-iter).
//   + C-operand fold: pp1.w = -(n1*L2E), C1 = qw - pw.w -> MFMA emits fd.
//
// ws (floats): pp1[0,32768) pp2[32768,65536) fragB[65536,196608)
// fragA[196608,327680) regp[327680,335872) part[335872,434176).

#define NPTS 4096
#define ROWS_TOT 8192
#define DF 32

#define L2E  1.4426950408889634f
#define LN2  0.6931471805599453f
#define FSC  1.6986436f          // sqrt(2*log2e)
#define PSC  240.2244f           // 200*sqrt(log2e)

typedef _Float16 half8 __attribute__((ext_vector_type(8)));
typedef float f4 __attribute__((ext_vector_type(4)));

// ---- kA: prep (R6 + negated n1' for C-fold) ----
__global__ void kA_prep(const float* __restrict__ pts,
                        const float* __restrict__ f1g,
                        const float* __restrict__ f2g,
                        float* __restrict__ pp1, float* __restrict__ pp2,
                        _Float16* __restrict__ fragA, _Float16* __restrict__ fragB,
                        float* __restrict__ regp, float* __restrict__ out) {
    const int r = blockIdx.x * 64 + threadIdx.x;     // 0..8191
    if (r < 4) out[r] = 0.0f;
    const int jt = r >> 4;                           // global tile id 0..511
    const int c  = r & 15;                           // row/col within tile

    float n1, n2, reg1, reg2;
    {
        const float4* f2v = (const float4*)(f2g + (size_t)r * DF);
        float vals[32];
        float s = 0.0f;
#pragma unroll
        for (int q = 0; q < 8; ++q) {
            float4 v = f2v[q];
            vals[4*q]=v.x; vals[4*q+1]=v.y; vals[4*q+2]=v.z; vals[4*q+3]=v.w;
            s += v.x*v.x + v.y*v.y + v.z*v.z + v.w*v.w;
        }
        n2 = s;
        reg2 = s - vals[0]*vals[0] - vals[1]*vals[1] - vals[2]*vals[2];
        half8* fv = (half8*)fragB;
#pragma unroll
        for (int kb = 0; kb < 4; ++kb) {             // lane-ordered slot
            half8 h;
#pragma unroll
            for (int i = 0; i < 8; ++i) h[i] = (_Float16)(vals[kb*8+i] * FSC);
            fv[(size_t)jt*64 + kb*16 + c] = h;
        }
    }
    {
        const float4* f1v = (const float4*)(f1g + (size_t)r * DF);
        float vals[32];
        float s = 0.0f;
#pragma unroll
        for (int q = 0; q < 8; ++q) {
            float4 v = f1v[q];
            vals[4*q]=v.x; vals[4*q+1]=v.y; vals[4*q+2]=v.z; vals[4*q+3]=v.w;
            s += v.x*v.x + v.y*v.y + v.z*v.z + v.w*v.w;
        }
        n1 = s;
        reg1 = s - vals[0]*vals[0] - vals[1]*vals[1] - vals[2]*vals[2];
        half8* fv = (half8*)fragA;
#pragma unroll
        for (int kb = 0; kb < 4; ++kb) {
            half8 h;
#pragma unroll
            for (int i = 0; i < 8; ++i) h[i] = (_Float16)(vals[kb*8+i] * FSC);
            fv[(size_t)jt*64 + kb*16 + c] = h;
        }
    }
    const float* pp = pts + (size_t)r * 3;
    const float px = pp[0]*PSC, py = pp[1]*PSC, pz = pp[2]*PSC;
    ((float4*)pp1)[r] = make_float4(px, py, pz, -(n1 * L2E));   // NEGATED (C-fold)
    ((float4*)pp2)[r] = make_float4(px, py, pz, n2 * L2E);
    regp[r] = reg1 + reg2;
}

// ---- kB: (i-quad, j-quarter) blocks; one B-load feeds four MFMAs ----
__launch_bounds__(512)
__global__ void kB_main(const float* __restrict__ pp1,
                        const float* __restrict__ pp2,
                        const _Float16* __restrict__ fragA,
                        const _Float16* __restrict__ fragB,
                        float* __restrict__ part) {
    __shared__ float sS[8][64], sT[8][64], sF[8][64];

    const int tid = threadIdx.x;
    const int l = tid & 63, wv = tid >> 6;           // wave 0..7
    const int ip4 = blockIdx.x >> 2;                 // i-quad 0..127
    const int jq  = blockIdx.x & 3;                  // j-quarter 0..3
    const int b   = ip4 >> 6;
    const int i0g = ip4 * 64;                        // 64-row base
    const int lr = l & 15, lk = l >> 4;

    half8 af[4];
    f4 qx[4], qy[4], qz[4], qw[4];
#pragma unroll
    for (int i = 0; i < 4; ++i) {
        af[i] = ((const half8*)fragA)[(size_t)(ip4 * 4 + i) * 64 + l];
        const int rb = i0g + i * 16 + lk * 4;
#pragma unroll
        for (int e = 0; e < 4; ++e) {
            const float4 q = ((const float4*)pp1)[rb + e];
            qx[i][e] = q.x; qy[i][e] = q.y; qz[i][e] = q.z; qw[i][e] = q.w;
        }
    }

    // wave's j range: 8 tiles, jt0 = b*256 + jq*64 + wv*8
    const int jt0 = b * 256 + jq * 64 + wv * 8;
    const int j0  = b * NPTS + jq * 1024 + wv * 128 + lr;
    const half8*  fbase = (const half8*)fragB + ((size_t)jt0 * 64 + l);
    const float4* pbase = (const float4*)pp2 + j0;

    f4 sp[4], tA[4], sf[4];
#pragma unroll
    for (int i = 0; i < 4; ++i) {
        sp[i] = (f4){0,0,0,0}; tA[i] = (f4){0,0,0,0}; sf[i] = (f4){0,0,0,0};
    }

    half8  bfC = fbase[0];
    float4 pwC = pbase[0];
#pragma unroll
    for (int t = 0; t < 8; ++t) {
        half8  bfN = bfC;
        float4 pwN = pwC;
        if (t < 7) {                                 // 1-deep prefetch
            bfN = fbase[(t + 1) * 64];
            pwN = pbase[(t + 1) * 16];
        }
#pragma unroll
        for (int i = 0; i < 4; ++i) {
            const f4 C1 = qw[i] - pwC.w;             // -(n1'+n2')
            const f4 fd = __builtin_amdgcn_mfma_f32_16x16x32_f16(af[i], bfC, C1, 0, 0, 0);
            const f4 dx = qx[i] - pwC.x;
            const f4 dy = qy[i] - pwC.y;
            const f4 dz = qz[i] - pwC.z;
            const f4 s  = dx*dx + dy*dy + dz*dz;     // log2e * |dp|^2
            f4 ep, ef;
#pragma unroll
            for (int e = 0; e < 4; ++e) {
                ep[e] = __builtin_amdgcn_exp2f(-s[e]);
                ef[e] = __builtin_amdgcn_exp2f(fd[e]);
            }
            sp[i] += ep;
            tA[i] += ep * fd;
            sf[i] += ef;
        }
        bfC = bfN;
        pwC = pwN;
    }

    // reduce over the 16 columns (lane bits 0..3), all 4 tiles
#pragma unroll
    for (int m = 1; m < 16; m <<= 1) {
#pragma unroll
        for (int i = 0; i < 4; ++i) {
#pragma unroll
            for (int e = 0; e < 4; ++e) {
                sp[i][e] += __shfl_xor(sp[i][e], m);
                tA[i][e] += __shfl_xor(tA[i][e], m);
                sf[i][e] += __shfl_xor(sf[i][e], m);
            }
        }
    }
    if (lr == 0) {
#pragma unroll
        for (int i = 0; i < 4; ++i) {
#pragma unroll
            for (int e = 0; e < 4; ++e) {
                sS[wv][i * 16 + lk * 4 + e] = sp[i][e];
                sT[wv][i * 16 + lk * 4 + e] = tA[i][e];
                sF[wv][i * 16 + lk * 4 + e] = sf[i][e];
            }
        }
    }
    __syncthreads();

    if (tid < 64) {
        float sp_ = 0.f, tp_ = 0.f, sf_ = 0.f;
#pragma unroll
        for (int w = 0; w < 8; ++w) {
            sp_ += sS[w][tid];
            tp_ += sT[w][tid];
            sf_ += sF[w][tid];
        }
        float* P = part + (size_t)jq * 3 * ROWS_TOT;
        P[i0g + tid]                = sp_;
        P[ROWS_TOT + i0g + tid]     = tp_;
        P[2 * ROWS_TOT + i0g + tid] = sf_;
    }
}

// ---- k2: combine 4 j-quarter planes, ce + reg -> out ----
__global__ void k2_final(const float* __restrict__ part,
                         const float* __restrict__ regp,
                         const float* __restrict__ wg,
                         float* __restrict__ out) {
    __shared__ float redc[4], redr[4];
    const int tid = threadIdx.x;
    const int r = blockIdx.x * 256 + tid;
    const int b = r >> 12;

    float sp_ = 0.f, tp_ = 0.f, sf_ = 0.f;
#pragma unroll
    for (int q = 0; q < 4; ++q) {
        const float* P = part + (size_t)q * 3 * ROWS_TOT;
        sp_ += P[r];
        tp_ += P[ROWS_TOT + r];
        sf_ += P[2 * ROWS_TOT + r];
    }
    const float ce = __logf(sf_) - (tp_ * LN2) / sp_;
    float contrib = wg[r] * ce;
    float rr = regp[r];

#pragma unroll
    for (int off = 32; off > 0; off >>= 1) {
        contrib += __shfl_down(contrib, off);
        rr      += __shfl_down(rr, off);
    }
    const int wave = tid >> 6, lane = tid & 63;
    if (lane == 0) { redc[wave] = contrib; redr[wave] = rr; }
    __syncthreads();
    if (tid == 0) {
        atomicAdd(&out[b],     redc[0] + redc[1] + redc[2] + redc[3]);
        atomicAdd(&out[2 + b], (redr[0] + redr[1] + redr[2] + redr[3])
                               * (1.0f / (29.0f * (float)NPTS)));
    }
}

extern "C" void kernel_launch(void* const* d_in, const int* in_sizes, int n_in,
                              void* d_out, int out_size, void* d_ws, size_t ws_size,
                              hipStream_t stream) {
    const float* pts = (const float*)d_in[0];
    const float* f1  = (const float*)d_in[1];
    const float* f2  = (const float*)d_in[2];
    const float* wg  = (const float*)d_in[3];
    float* out = (float*)d_out;

    float* ws = (float*)d_ws;
    float*     pp1   = ws;                           // 32768
    float*     pp2   = ws + 32768;                   // 32768
    _Float16*  fragB = (_Float16*)(ws + 65536);      // 262144 halves
    _Float16*  fragA = (_Float16*)(ws + 196608);     // 262144 halves
    float*     regp  = ws + 327680;                  // 8192
    float*     part  = ws + 335872;                  // 4*3*8192 = 98304

    kA_prep<<<ROWS_TOT / 64, 64, 0, stream>>>(pts, f1, f2, pp1, pp2,
                                              fragA, fragB, regp, out);
    kB_main<<<512, 512, 0, stream>>>(pp1, pp2, fragA, fragB, part);
    k2_final<<<ROWS_TOT / 256, 256, 0, stream>>>(part, regp, wg, out);
}